// Round 1
// 105.072 us; speedup vs baseline: 1.0552x; 1.0552x over previous
//
#include <hip/hip_runtime.h>
#include <math.h>

#define B 4
#define N 512
#define IN_DIM 128
#define OUT_DIM 128
#define HEADS 4
#define PER_HEAD 32
#define NT (N / 64)        // 8 j-tiles of 64
#define IT 4               // target nodes per block (attn) -- was 2
#define LROWS 4            // rows per block (linear)
#define LIN_BLOCKS (B * N / LROWS)   // 512
#define MASK_BLOCKS 512

// R10. Two structural findings from the R9 profile:
//  (a) top-5 dispatches are all 41.5us harness ws-poison fills (256MiB) ->
//      ~83us of dur_us is a fixed floor; our kernels are the remaining ~28us.
//  (b) gat_attn was L2-BW-bound: 4096 blocks x 128KB/block = 512MB L2 traffic
//      (~15us at 34.5TB/s) vs a ~5-6us VALU floor.
// Changes: IT 2->4 (halves L2 traffic; phase-1 split into two c-halves of 16
// to keep VGPRs ~150, same 8-waves/CU bucket); packed-f32 math (v_pk_add/max/
// fma) cuts the score loop 4->3 insts per 2 channels; gat_mask folded into
// the linear launch as a fat kernel with 512 one-(b,itile,t,half) sub-blocks
// (16 adj loads/lane, u16 stores) instead of 32 blocks x 128 loads/lane.

typedef float v2f __attribute__((ext_vector_type(2)));

static __device__ inline v2f mk2(float a, float b) {
    v2f r; r.x = a; r.y = b; return r;
}

// ---------------------------------------------------------------------------
// Kernel 1 (fat): blocks [0,512): xl = x@Wl+bl ; xr = x@Wr+br, xlT in
// channel-group-of-4 layout, plus axl/axr att-dots (half-wave reduce).
// Blocks [512,1024): adjacency bitmask, transposed, diagonal forced --
// one (b, i-tile64, t, u32-half) per block, 2 waves x 16 j each, u16 stores.
// ---------------------------------------------------------------------------
__global__ __launch_bounds__(128) void gat_prep(
    const float* __restrict__ x, const float* __restrict__ Wl,
    const float* __restrict__ bl, const float* __restrict__ Wr,
    const float* __restrict__ br, const float* __restrict__ att,
    const int* __restrict__ adj,
    float* __restrict__ xl, float* __restrict__ xr, float* __restrict__ xlT,
    float* __restrict__ axl, float* __restrict__ axr,
    unsigned long long* __restrict__ maskT) {
    const int bid = blockIdx.x;
    __shared__ float xs[LROWS][IN_DIM];

    if (bid < LIN_BLOCKS) {
        // ---- linear role (verified R4/R9 code, unchanged) ----
        const int r0  = bid * LROWS;
        const int col = threadIdx.x;          // col = h*32 + c
#pragma unroll
        for (int r = 0; r < LROWS; ++r)
            xs[r][col] = x[(r0 + r) * IN_DIM + col];
        __syncthreads();

        float accl[LROWS], accr[LROWS];
        {
            const float blv = bl[col];
            const float brv = br[col];
#pragma unroll
            for (int r = 0; r < LROWS; ++r) { accl[r] = blv; accr[r] = brv; }
        }
#pragma unroll 8
        for (int k = 0; k < IN_DIM; ++k) {
            const float wl = Wl[k * OUT_DIM + col];
            const float wr = Wr[k * OUT_DIM + col];
#pragma unroll
            for (int r = 0; r < LROWS; ++r) {
                accl[r] = fmaf(xs[r][k], wl, accl[r]);
                accr[r] = fmaf(xs[r][k], wr, accr[r]);
            }
        }
        const float attc = att[col];
        const int h = col >> 5;
#pragma unroll
        for (int r = 0; r < LROWS; ++r) {
            const int row = r0 + r;
            const int b = row >> 9, n = row & (N - 1);
            xl[row * OUT_DIM + col] = accl[r];
            xr[row * OUT_DIM + col] = accr[r];
            xlT[((b * 32 + (col >> 2)) * N + n) * 4 + (col & 3)] = accl[r];
            float pl = attc * accl[r];
            float pr = attc * accr[r];
#pragma unroll
            for (int d = 1; d < 32; d <<= 1) {
                pl += __shfl_xor(pl, d);
                pr += __shfl_xor(pr, d);
            }
            if ((col & 31) == 0) {
                axl[(b * HEADS + h) * N + n] = pl;
                axr[(b * HEADS + h) * N + n] = pr;
            }
        }
    } else {
        // ---- mask role: 512 sub-blocks, 16 adj loads per lane ----
        const int mid  = bid - LIN_BLOCKS;    // 0..511
        const int mb   = mid >> 7;            // batch
        const int it6  = (mid >> 4) & 7;      // i-tile of 64
        const int th   = mid & 15;
        const int t    = th >> 1;             // j-tile of 64
        const int half = th & 1;              // which u32 of the u64
        const int w    = threadIdx.x >> 6;    // wave: low/high u16 of the u32
        const int i    = it6 * 64 + (threadIdx.x & 63);
        const int j0   = t * 64 + half * 32 + w * 16;
        unsigned int bits = 0;
#pragma unroll
        for (int k = 0; k < 16; ++k) {
            const int j = j0 + k;
            bits |= (unsigned int)(adj[((size_t)mb * N + j) * N + i] != 0) << k;
        }
        // self-loop: bit (i&63) of tile t, if it falls in this u16
        const int p = (i & 63) - (half * 32 + w * 16);
        if ((i >> 6) == t && (unsigned)p < 16u) bits |= 1u << p;
        unsigned short* m16 = (unsigned short*)maskT;
        m16[(((size_t)mb * N + i) * NT + t) * 4 + half * 2 + w] =
            (unsigned short)bits;
    }
}

// ---------------------------------------------------------------------------
// Kernel 2: fused scores + segment-softmax + aggregation. 1 wave per block,
// IT=4 targets, phase-1 c-halved to bound VGPRs, packed-f32 inner loops.
// ---------------------------------------------------------------------------
__global__ __launch_bounds__(64) void gat_attn(
    const float* __restrict__ xl, const float* __restrict__ xr,
    const float* __restrict__ xlT, const float* __restrict__ axl,
    const float* __restrict__ axr,
    const unsigned long long* __restrict__ maskT,
    const float* __restrict__ att, const float* __restrict__ bias,
    float* __restrict__ out) {
    const int lane = threadIdx.x;         // 0..63 (one wave)
    const int h    = blockIdx.y;          // head
    const int i0   = blockIdx.x * IT;
    const int b    = blockIdx.z;

    __shared__ float a_s[IT][N];          // 8 KB

    // ---- Phase 1: att-dot |x_i + x_j| term, two c-halves of 16 ----
    float e[IT][NT];
#pragma unroll
    for (int ii = 0; ii < IT; ++ii)
#pragma unroll
        for (int t = 0; t < NT; ++t) e[ii][t] = 0.f;

    const float4* xlT4 = (const float4*)xlT + (size_t)(b * 32 + h * 8) * N;

#pragma unroll
    for (int ch = 0; ch < 2; ++ch) {
        v2f att2[8];
#pragma unroll
        for (int cc = 0; cc < 8; ++cc) {
            const int c = h * PER_HEAD + ch * 16 + cc * 2;
            att2[cc] = mk2(0.4f * att[c], 0.4f * att[c + 1]);
        }
        v2f xr2[IT][8];
#pragma unroll
        for (int ii = 0; ii < IT; ++ii) {
            const float4* xrp = (const float4*)(
                xr + (size_t)(b * N + i0 + ii) * OUT_DIM + h * PER_HEAD + ch * 16);
#pragma unroll
            for (int q = 0; q < 4; ++q) {
                const float4 v = xrp[q];
                xr2[ii][q * 2 + 0] = mk2(v.x, v.y);
                xr2[ii][q * 2 + 1] = mk2(v.z, v.w);
            }
        }
#pragma unroll
        for (int jt = 0; jt < NT; ++jt) {
            const int j = jt * 64 + lane;
            v2f xlv[8];
#pragma unroll
            for (int q = 0; q < 4; ++q) {
                const float4 v = xlT4[(ch * 4 + q) * N + j];
                xlv[q * 2 + 0] = mk2(v.x, v.y);
                xlv[q * 2 + 1] = mk2(v.z, v.w);
            }
#pragma unroll
            for (int ii = 0; ii < IT; ++ii) {
                v2f acc = mk2(0.f, 0.f);
#pragma unroll
                for (int cc = 0; cc < 8; ++cc) {
                    v2f s = xr2[ii][cc] + xlv[cc];        // v_pk_add_f32
                    s = __builtin_elementwise_max(s, -s); // v_pk_max_f32 (neg mod)
                    acc = __builtin_elementwise_fma(att2[cc], s, acc); // v_pk_fma_f32
                }
                e[ii][jt] += acc.x + acc.y;
            }
        }
    }

    // ---- finalize scores: 0.6*(axr_i + axl_j) + mask ----
    float axr_i[IT];
#pragma unroll
    for (int ii = 0; ii < IT; ++ii)
        axr_i[ii] = axr[(b * HEADS + h) * N + i0 + ii];
    const float* axlh = axl + (size_t)(b * HEADS + h) * N;
#pragma unroll
    for (int jt = 0; jt < NT; ++jt) {
        const int j = jt * 64 + lane;
        const float alj = axlh[j];
#pragma unroll
        for (int ii = 0; ii < IT; ++ii) {
            const float ev = fmaf(0.6f, axr_i[ii] + alj, e[ii][jt]);
            const unsigned long long m =
                maskT[(size_t)(b * N + i0 + ii) * NT + jt];
            e[ii][jt] = ((m >> lane) & 1ull) ? ev : -1e30f;
        }
    }

    // ---- Phase 2: softmax (register), unnormalized alpha -> LDS ----
    float inv[IT];
#pragma unroll
    for (int ii = 0; ii < IT; ++ii) {
        float m = e[ii][0];
#pragma unroll
        for (int t = 1; t < NT; ++t) m = fmaxf(m, e[ii][t]);
#pragma unroll
        for (int d = 1; d < 64; d <<= 1) m = fmaxf(m, __shfl_xor(m, d));
        float ssum = 0.f;
#pragma unroll
        for (int t = 0; t < NT; ++t) {
            const float a = __expf(e[ii][t] - m);
            a_s[ii][t * 64 + lane] = a;
            ssum += a;
        }
#pragma unroll
        for (int d = 1; d < 64; d <<= 1) ssum += __shfl_xor(ssum, d);
        inv[ii] = 1.f / ssum;
    }
    // same wave wrote a_s -> no barrier needed

    // ---- Phase 3: aggregation; jo-outer shares each float4 across IT ----
    const int c4 = (lane & 7) * 4;
    const int jg = lane >> 3;
    const float* xlb = xl + (size_t)(b * N) * OUT_DIM + h * PER_HEAD + c4;

    v2f accA[IT], accB[IT];
#pragma unroll
    for (int ii = 0; ii < IT; ++ii) {
        accA[ii] = mk2(0.f, 0.f);
        accB[ii] = mk2(0.f, 0.f);
    }

#pragma unroll 8
    for (int jo = 0; jo < N / 8; ++jo) {
        const int j = jo * 8 + jg;
        const float4 xv = *(const float4*)(xlb + (size_t)j * OUT_DIM);
        const v2f x0 = mk2(xv.x, xv.y);
        const v2f x1 = mk2(xv.z, xv.w);
#pragma unroll
        for (int ii = 0; ii < IT; ++ii) {
            const float av = a_s[ii][j];
            const v2f av2 = mk2(av, av);
            accA[ii] = __builtin_elementwise_fma(av2, x0, accA[ii]);
            accB[ii] = __builtin_elementwise_fma(av2, x1, accB[ii]);
        }
    }

#pragma unroll
    for (int ii = 0; ii < IT; ++ii) {
        float rx = accA[ii].x, ry = accA[ii].y;
        float rz = accB[ii].x, rw = accB[ii].y;
#pragma unroll
        for (int d = 8; d < 64; d <<= 1) {
            rx += __shfl_xor(rx, d);
            ry += __shfl_xor(ry, d);
            rz += __shfl_xor(rz, d);
            rw += __shfl_xor(rw, d);
        }
        if (jg == 0) {
            const float s = inv[ii];
            const int ob = (b * N + i0 + ii) * OUT_DIM + h * PER_HEAD + c4;
            const float4 r = make_float4(rx * s + bias[h * PER_HEAD + c4 + 0],
                                         ry * s + bias[h * PER_HEAD + c4 + 1],
                                         rz * s + bias[h * PER_HEAD + c4 + 2],
                                         rw * s + bias[h * PER_HEAD + c4 + 3]);
            *(float4*)(out + ob) = r;
        }
    }
}

extern "C" void kernel_launch(void* const* d_in, const int* in_sizes, int n_in,
                              void* d_out, int out_size, void* d_ws, size_t ws_size,
                              hipStream_t stream) {
    const float* x    = (const float*)d_in[0];
    const int*   adj  = (const int*)d_in[1];
    const float* Wl   = (const float*)d_in[2];
    const float* bl   = (const float*)d_in[3];
    const float* Wr   = (const float*)d_in[4];
    const float* br   = (const float*)d_in[5];
    const float* att  = (const float*)d_in[6];
    const float* bias = (const float*)d_in[7];
    float* out = (float*)d_out;

    char* ws = (char*)d_ws;
    float* xl   = (float*)(ws);                         // 1 MB
    float* xr   = (float*)(ws + (1u << 20));            // 1 MB
    float* xlT  = (float*)(ws + (2u << 20));            // 1 MB
    unsigned long long* maskT =
        (unsigned long long*)(ws + (3u << 20));         // 128 KB
    float* axl  = (float*)(ws + (3u << 20) + (1u << 17));              // 32 KB
    float* axr  = (float*)(ws + (3u << 20) + (1u << 17) + (1u << 15)); // 32 KB

    gat_prep<<<dim3(LIN_BLOCKS + MASK_BLOCKS), dim3(128), 0, stream>>>(
        x, Wl, bl, Wr, br, att, adj, xl, xr, xlT, axl, axr, maskT);
    gat_attn<<<dim3(N / IT, HEADS, B), dim3(64), 0, stream>>>(
        xl, xr, xlT, axl, axr, maskT, att, bias, out);
}